// Round 9
// baseline (114.662 us; speedup 1.0000x reference)
//
#include <hip/hip_runtime.h>
#include <stdint.h>
#include <stddef.h>

typedef __attribute__((ext_vector_type(8))) short bf16x8;
typedef __attribute__((ext_vector_type(4))) float f32x4;
typedef __attribute__((ext_vector_type(4))) int i32x4;

#define NH 128
#define NW 128
#define NC 64
#define NF 256
#define SLOT 16384                 // one x-row image: [w=128][cb=8 x 16B], XOR-swizzled
#define XOFF 294912                // byte offset of x images in ws (after 288 KB B table)
#define WS_NEED (XOFF + 2048 * SLOT)

__device__ __forceinline__ unsigned short f2b(float f) {
  union { float f; uint32_t u; } t; t.f = f;
  uint32_t u = t.u;
  return (unsigned short)((u + 0x7fffu + ((u >> 16) & 1u)) >> 16);
}

__device__ __forceinline__ void gload16(const void* g, void* l) {
  __builtin_amdgcn_global_load_lds(
      (const __attribute__((address_space(1))) unsigned int*)g,
      (__attribute__((address_space(3))) unsigned int*)l, 16, 0, 0);
}

// Combined prep (R8-verified, unchanged):
//  blocks [0,72):   B table in per-wave fragment order:
//    u16 elem ((fi*9+s)*16 + cf*2 + kk)*512 + lane*8 + e
//      = kern[(s*64 + (kk*4+(lane>>4))*8 + e)*NF + fi*128 + cf*16 + (lane&15)]
//  blocks [72,...): x -> bf16 swizzled 16KB row-images at XOFF (DMA path):
//    image (b*128+h), byte w*128 + ((cb^(w&7))<<4) = x[b,h,w,cb*8..+8]
__global__ void prep_all(const float* __restrict__ x, const float* __restrict__ kr,
                         unsigned short* __restrict__ ws) {
  int bid = (int)blockIdx.x;
  if (bid < 72) {
    int t = bid * 256 + threadIdx.x;   // [0, 18432)
    int lane = t & 63;
    int kk   = (t >> 6) & 1;
    int cf   = (t >> 7) & 7;
    int rest = t >> 10;          // fi*9 + s
    int s  = rest % 9;
    int fi = rest / 9;
    int l15 = lane & 15, l4 = lane >> 4;
    int col = fi * 128 + cf * 16 + l15;
    int k0  = s * 64 + (kk * 4 + l4) * 8;
    unsigned short* dst = ws + (size_t)t * 8;
    const float* src = kr + (size_t)k0 * NF + col;
    #pragma unroll
    for (int e = 0; e < 8; ++e) dst[e] = f2b(src[(size_t)e * NF]);
  } else {
    int idx = (bid - 72) * 256 + threadIdx.x;   // [0, 2097152) 16B tasks
    int q   = idx & 1023;
    int row = idx >> 10;                        // b*128+h
    int w = q >> 3, cb = q & 7;
    const float* src = x + ((size_t)row * NW + w) * NC + cb * 8;
    float4 a0 = *(const float4*)(src);
    float4 a1 = *(const float4*)(src + 4);
    union { unsigned short u[8]; i32x4 v; } p;
    p.u[0] = f2b(a0.x); p.u[1] = f2b(a0.y); p.u[2] = f2b(a0.z); p.u[3] = f2b(a0.w);
    p.u[4] = f2b(a1.x); p.u[5] = f2b(a1.y); p.u[6] = f2b(a1.z); p.u[7] = f2b(a1.w);
    *(i32x4*)((char*)ws + XOFF + (size_t)row * SLOT + w * 128 + ((cb ^ (w & 7)) << 4)) = p.v;
  }
}

// conv: block = one (b,h) x half-N(128F). 4 waves, wave tile 128w x 32F.
// B: ALL 9 shifts register-resident (36 bf16x8 = 144 VGPR / wave), loaded
// ONCE in prologue under the A-DMA. Main loop = ds_read_b128 + MFMA ONLY.
template<bool DMA_A>
__global__ __launch_bounds__(256, 2)
void conv_main(const float* __restrict__ x, const unsigned short* __restrict__ bt,
               const float* __restrict__ bias, float* __restrict__ out)
{
  __shared__ __align__(16) char lds[3 * SLOT];   // 48 KB; epilogue reuses

  const int tid  = threadIdx.x;
  const int lane = tid & 63;
  const int l15  = lane & 15;
  const int l4   = lane >> 4;
  const int wn   = tid >> 6;    // wave id 0..3 = F-quarter (32 cols)

  // XCD-aware bijective swizzle: nwg=4096, 512 per XCD.
  int bid  = (int)blockIdx.x;
  int work = (bid & 7) * 512 + (bid >> 3);
  int mi = work >> 1;           // (b,h) flat
  int fi = work & 1;
  int bb = mi >> 7;
  int hh = mi & 127;
  int F0 = fi * 128;

  const char* bimg = (const char*)bt + (size_t)fi * 9 * 16384;
  const char* bwv  = bimg + wn * 4096 + lane * 16;  // + s*16384 + c*2048 + kk*1024

  bf16x8 breg[9][2][2];   // entire B for this wave, all 9 shifts — static idx

  // ---- prologue: issue ALL B loads (once per kernel), then stage A ----
  #pragma unroll
  for (int s = 0; s < 9; ++s)
    #pragma unroll
    for (int c = 0; c < 2; ++c)
      #pragma unroll
      for (int kk = 0; kk < 2; ++kk)
        breg[s][c][kk] = *(const bf16x8*)(bwv + s * 16384 + c * 2048 + kk * 1024);

  // ---- stage A rows h-1,h,h+1 -> slots 0..2 ----
  if constexpr (DMA_A) {
    const char* xim = (const char*)bt + XOFF;
    #pragma unroll
    for (int r = 0; r < 3; ++r) {
      int xr = (hh + r + 127) & 127;
      const char* src = xim + ((size_t)(bb * NH + xr)) * SLOT;
      #pragma unroll
      for (int i = 0; i < 4; ++i) {
        int byte = tid * 16 + i * 4096;
        gload16(src + byte, lds + r * SLOT + byte);
      }
    }
  } else {
    #pragma unroll
    for (int i = 0; i < 12; ++i) {
      int idx = tid + i * 256;
      int cb = idx & 7;
      int w  = (idx >> 3) & 127;
      int r  = idx >> 10;
      int xr = (hh + r + 127) & 127;
      const float* src = x + (((size_t)(bb * NH + xr) * NW + w) * NC + cb * 8);
      float4 a0 = *(const float4*)(src);
      float4 a1 = *(const float4*)(src + 4);
      union { unsigned short u[8]; i32x4 v; } p;
      p.u[0] = f2b(a0.x); p.u[1] = f2b(a0.y); p.u[2] = f2b(a0.z); p.u[3] = f2b(a0.w);
      p.u[4] = f2b(a1.x); p.u[5] = f2b(a1.y); p.u[6] = f2b(a1.z); p.u[7] = f2b(a1.w);
      *(i32x4*)(lds + (r * SLOT + w * 128 + ((cb ^ (w & 7)) << 4))) = p.v;
    }
  }
  __syncthreads();    // drains DMA vmcnt + B loads; A read-only hereafter

  // A-address LUT (6 scalars): for dw = 1-dwi,
  //   addr(m) = slotb + ((m*2048 + trow) & 16383) + swz,  kk=1 = XOR 64
  int trow[3], swz[3];
  #pragma unroll
  for (int dwi = 0; dwi < 3; ++dwi) {
    int t = l15 + 1 - dwi;                 // -1..16
    trow[dwi] = (t & 127) * 128;
    swz[dwi]  = (l4 ^ (t & 7)) << 4;
  }

  f32x4 acc[8][2];
  #pragma unroll
  for (int m = 0; m < 8; ++m)
    #pragma unroll
    for (int n = 0; n < 2; ++n)
      acc[m][n] = (f32x4){0.f, 0.f, 0.f, 0.f};

  #pragma unroll
  for (int s = 0; s < 9; ++s) {
    const int dwi   = s / 3;                  // static
    const int slotb = (2 - (s % 3)) * SLOT;   // static
    #pragma unroll
    for (int kk = 0; kk < 2; ++kk) {
      #pragma unroll
      for (int mh = 0; mh < 2; ++mh) {        // m in halves: af stays 16 VGPR
        bf16x8 af[4];
        #pragma unroll
        for (int m4 = 0; m4 < 4; ++m4) {
          int m = mh * 4 + m4;
          int addr = slotb + ((m * 2048 + trow[dwi]) & 16383) + swz[dwi];
          af[m4] = *(const bf16x8*)(lds + (addr ^ (kk << 6)));
        }
        #pragma unroll
        for (int m4 = 0; m4 < 4; ++m4)
          #pragma unroll
          for (int n = 0; n < 2; ++n)
            acc[mh * 4 + m4][n] = __builtin_amdgcn_mfma_f32_16x16x32_bf16(
                af[m4], breg[s][n][kk], acc[mh * 4 + m4][n], 0, 0, 0);
      }
    }
  }

  // ---- epilogue: bias + FULL-LINE stores via LDS transpose ----
  float bv[2];
  #pragma unroll
  for (int n = 0; n < 2; ++n) bv[n] = bias[F0 + wn * 32 + n * 16 + l15];

  __syncthreads();
  float* eb = (float*)lds;              // [64][132] padded f32 tile

  #pragma unroll
  for (int chunk = 0; chunk < 2; ++chunk) {
    #pragma unroll
    for (int m4 = 0; m4 < 4; ++m4) {    // every wave deposits its 32-col slice
      int m = chunk * 4 + m4;
      #pragma unroll
      for (int jj = 0; jj < 4; ++jj) {
        int r = m4 * 16 + l4 * 4 + jj;                // chunk-local row
        #pragma unroll
        for (int n = 0; n < 2; ++n)
          eb[r * 132 + wn * 32 + n * 16 + l15] = acc[m][n][jj] + bv[n];
      }
    }
    __syncthreads();
    size_t obase = ((size_t)mi * 128 + chunk * 64) * NF + F0;
    #pragma unroll
    for (int i = 0; i < 8; ++i) {
      int r = i * 8 + wn * 2 + (lane >> 5);           // 0..63
      int c = (lane & 31) * 4;                        // 0..124
      f32x4 v = *(const f32x4*)(eb + r * 132 + c);
      *(f32x4*)(out + obase + (size_t)r * NF + c) = v;
    }
    if (chunk == 0) __syncthreads();
  }
}

extern "C" void kernel_launch(void* const* d_in, const int* in_sizes, int n_in,
                              void* d_out, int out_size, void* d_ws, size_t ws_size,
                              hipStream_t stream) {
  const float* x    = (const float*)d_in[0];
  const float* kern = (const float*)d_in[1];
  const float* bias = (const float*)d_in[2];
  float* out = (float*)d_out;
  unsigned short* bt = (unsigned short*)d_ws;

  if (ws_size >= (size_t)WS_NEED) {
    prep_all<<<dim3(72 + 8192), dim3(256), 0, stream>>>(x, kern, bt);
    conv_main<true><<<dim3(4096), dim3(256), 0, stream>>>(x, bt, bias, out);
  } else {
    prep_all<<<dim3(72), dim3(256), 0, stream>>>(x, kern, bt);
    conv_main<false><<<dim3(4096), dim3(256), 0, stream>>>(x, bt, bias, out);
  }
}

// Round 10
// 113.006 us; speedup vs baseline: 1.0147x; 1.0147x over previous
//
#include <hip/hip_runtime.h>
#include <stdint.h>
#include <stddef.h>

typedef __attribute__((ext_vector_type(8))) short bf16x8;
typedef __attribute__((ext_vector_type(4))) float f32x4;
typedef __attribute__((ext_vector_type(4))) int i32x4;

#define NH 128
#define NW 128
#define NC 64
#define NF 256
#define SLOT 16384                 // one x-row image: [w=128][cb=8 x 16B], XOR-swizzled
#define XOFF 294912                // byte offset of x images in ws (after 288 KB B table)
#define WS_NEED (XOFF + 2048 * SLOT)

__device__ __forceinline__ unsigned short f2b(float f) {
  union { float f; uint32_t u; } t; t.f = f;
  uint32_t u = t.u;
  return (unsigned short)((u + 0x7fffu + ((u >> 16) & 1u)) >> 16);
}

__device__ __forceinline__ void gload16(const void* g, void* l) {
  __builtin_amdgcn_global_load_lds(
      (const __attribute__((address_space(1))) unsigned int*)g,
      (__attribute__((address_space(3))) unsigned int*)l, 16, 0, 0);
}

// Combined prep (R8-verified, unchanged):
//  blocks [0,72):   B table in per-wave fragment order:
//    u16 elem ((fi*9+s)*16 + cf*2 + kk)*512 + lane*8 + e
//      = kern[(s*64 + (kk*4+(lane>>4))*8 + e)*NF + fi*128 + cf*16 + (lane&15)]
//  blocks [72,...): x -> bf16 swizzled 16KB row-images at XOFF (DMA path):
//    image (b*128+h), byte w*128 + ((cb^(w&7))<<4) = x[b,h,w,cb*8..+8]
__global__ void prep_all(const float* __restrict__ x, const float* __restrict__ kr,
                         unsigned short* __restrict__ ws) {
  int bid = (int)blockIdx.x;
  if (bid < 72) {
    int t = bid * 256 + threadIdx.x;   // [0, 18432)
    int lane = t & 63;
    int kk   = (t >> 6) & 1;
    int cf   = (t >> 7) & 7;
    int rest = t >> 10;          // fi*9 + s
    int s  = rest % 9;
    int fi = rest / 9;
    int l15 = lane & 15, l4 = lane >> 4;
    int col = fi * 128 + cf * 16 + l15;
    int k0  = s * 64 + (kk * 4 + l4) * 8;
    unsigned short* dst = ws + (size_t)t * 8;
    const float* src = kr + (size_t)k0 * NF + col;
    #pragma unroll
    for (int e = 0; e < 8; ++e) dst[e] = f2b(src[(size_t)e * NF]);
  } else {
    int idx = (bid - 72) * 256 + threadIdx.x;   // [0, 2097152) 16B tasks
    int q   = idx & 1023;
    int row = idx >> 10;                        // b*128+h
    int w = q >> 3, cb = q & 7;
    const float* src = x + ((size_t)row * NW + w) * NC + cb * 8;
    float4 a0 = *(const float4*)(src);
    float4 a1 = *(const float4*)(src + 4);
    union { unsigned short u[8]; i32x4 v; } p;
    p.u[0] = f2b(a0.x); p.u[1] = f2b(a0.y); p.u[2] = f2b(a0.z); p.u[3] = f2b(a0.w);
    p.u[4] = f2b(a1.x); p.u[5] = f2b(a1.y); p.u[6] = f2b(a1.z); p.u[7] = f2b(a1.w);
    *(i32x4*)((char*)ws + XOFF + (size_t)row * SLOT + w * 128 + ((cb ^ (w & 7)) << 4)) = p.v;
  }
}

// conv (R8 structure at 3 blocks/CU): block = one (b,h) x half-N(128F),
// 4 waves, wave tile 64w x 64F. A via DMA from pre-swizzled images; B via
// register DOUBLE buffer (depth-1 safe: single 9-shift pass, no j-loop).
// VGPR budget ~165 <= 170 cap so 3 blocks/CU (LDS 3x48=144 <= 160 KB).
template<bool DMA_A>
__global__ __launch_bounds__(256, 3)
void conv_main(const float* __restrict__ x, const unsigned short* __restrict__ bt,
               const float* __restrict__ bias, float* __restrict__ out)
{
  __shared__ __align__(16) char lds[3 * SLOT];   // 48 KB; epilogue reuses

  const int tid  = threadIdx.x;
  const int lane = tid & 63;
  const int l15  = lane & 15;
  const int l4   = lane >> 4;
  const int wid  = tid >> 6;
  const int wm   = wid >> 1;    // 2: w-half
  const int wn   = wid & 1;     // 2: F-half (64 cols)

  // XCD-aware bijective swizzle: nwg=4096, 512 per XCD.
  int bid  = (int)blockIdx.x;
  int work = (bid & 7) * 512 + (bid >> 3);
  int mi = work >> 1;           // (b,h) flat
  int fi = work & 1;
  int bb = mi >> 7;
  int hh = mi & 127;
  int F0 = fi * 128;

  const char* bimg = (const char*)bt + (size_t)fi * 9 * 16384;
  const int boff = (wn * 4) * 2048 + lane * 16;

  bf16x8 breg[2][4][2];   // double buffer, all-static indices

  // ---- prologue: B(0) -> buf0 ----
  #pragma unroll
  for (int n = 0; n < 4; ++n)
    #pragma unroll
    for (int kk = 0; kk < 2; ++kk)
      breg[0][n][kk] = *(const bf16x8*)(bimg + boff + n * 2048 + kk * 1024);

  // ---- stage A rows h-1,h,h+1 -> slots 0..2 ----
  if constexpr (DMA_A) {
    const char* xim = (const char*)bt + XOFF;
    #pragma unroll
    for (int r = 0; r < 3; ++r) {
      int xr = (hh + r + 127) & 127;
      const char* src = xim + ((size_t)(bb * NH + xr)) * SLOT;
      #pragma unroll
      for (int i = 0; i < 4; ++i) {
        int byte = tid * 16 + i * 4096;
        gload16(src + byte, lds + r * SLOT + byte);
      }
    }
  } else {
    #pragma unroll
    for (int i = 0; i < 12; ++i) {
      int idx = tid + i * 256;
      int cb = idx & 7;
      int w  = (idx >> 3) & 127;
      int r  = idx >> 10;
      int xr = (hh + r + 127) & 127;
      const float* src = x + (((size_t)(bb * NH + xr) * NW + w) * NC + cb * 8);
      float4 a0 = *(const float4*)(src);
      float4 a1 = *(const float4*)(src + 4);
      union { unsigned short u[8]; i32x4 v; } p;
      p.u[0] = f2b(a0.x); p.u[1] = f2b(a0.y); p.u[2] = f2b(a0.z); p.u[3] = f2b(a0.w);
      p.u[4] = f2b(a1.x); p.u[5] = f2b(a1.y); p.u[6] = f2b(a1.z); p.u[7] = f2b(a1.w);
      *(i32x4*)(lds + (r * SLOT + w * 128 + ((cb ^ (w & 7)) << 4))) = p.v;
    }
  }
  __syncthreads();    // drains DMA vmcnt + B0; A read-only hereafter

  // compressed A-address LUT (6 scalars; the XOR term is m-invariant
  // since wm*64 and m*16 are both 0 mod 8):
  //   addr(m,dwi) = slotb + ((trow[dwi] + m*2048) & 16383) + swz[dwi]
  //   kk=1 address = kk=0 address XOR 64
  int trow[3], swz[3];
  #pragma unroll
  for (int dwi = 0; dwi < 3; ++dwi) {
    int t = l15 + 1 - dwi;
    trow[dwi] = ((wm * 64 + t) & 127) * 128;
    swz[dwi]  = (l4 ^ (t & 7)) << 4;
  }

  f32x4 acc[4][4];
  #pragma unroll
  for (int m = 0; m < 4; ++m)
    #pragma unroll
    for (int n = 0; n < 4; ++n)
      acc[m][n] = (f32x4){0.f, 0.f, 0.f, 0.f};

  #pragma unroll
  for (int s = 0; s < 9; ++s) {
    if (s < 8) {  // depth-1 prefetch: B(s+1) -> other buffer (consumed buf)
      const char* bs = bimg + (size_t)(s + 1) * 16384 + boff;
      #pragma unroll
      for (int n = 0; n < 4; ++n)
        #pragma unroll
        for (int kk = 0; kk < 2; ++kk)
          breg[(s + 1) & 1][n][kk] = *(const bf16x8*)(bs + n * 2048 + kk * 1024);
    }
    const int dwi   = s / 3;                  // static
    const int slotb = (2 - (s % 3)) * SLOT;   // static
    #pragma unroll
    for (int kk = 0; kk < 2; ++kk) {
      bf16x8 af[4];
      #pragma unroll
      for (int m = 0; m < 4; ++m) {
        int addr = slotb + ((trow[dwi] + m * 2048) & 16383) + swz[dwi];
        af[m] = *(const bf16x8*)(lds + (addr ^ (kk << 6)));
      }
      #pragma unroll
      for (int m = 0; m < 4; ++m)
        #pragma unroll
        for (int n = 0; n < 4; ++n)
          acc[m][n] = __builtin_amdgcn_mfma_f32_16x16x32_bf16(
              af[m], breg[s & 1][n][kk], acc[m][n], 0, 0, 0);
    }
  }

  // ---- epilogue: bias + FULL-LINE stores via LDS transpose (R8-verified) ----
  float bv[4];
  #pragma unroll
  for (int n = 0; n < 4; ++n) bv[n] = bias[F0 + wn * 64 + n * 16 + l15];

  __syncthreads();
  float* eb = (float*)lds;              // [64][132] padded f32 tile

  #pragma unroll
  for (int chunk = 0; chunk < 2; ++chunk) {
    if (wm == chunk) {
      #pragma unroll
      for (int m = 0; m < 4; ++m)
        #pragma unroll
        for (int jj = 0; jj < 4; ++jj) {
          int r = m * 16 + l4 * 4 + jj;
          #pragma unroll
          for (int n = 0; n < 4; ++n)
            eb[r * 132 + wn * 64 + n * 16 + l15] = acc[m][n][jj] + bv[n];
        }
    }
    __syncthreads();
    size_t obase = ((size_t)mi * 128 + chunk * 64) * NF + F0;
    #pragma unroll
    for (int i = 0; i < 8; ++i) {
      int r = i * 8 + wid * 2 + (lane >> 5);
      int c = (lane & 31) * 4;
      f32x4 v = *(const f32x4*)(eb + r * 132 + c);
      *(f32x4*)(out + obase + (size_t)r * NF + c) = v;
    }
    if (chunk == 0) __syncthreads();
  }
}

extern "C" void kernel_launch(void* const* d_in, const int* in_sizes, int n_in,
                              void* d_out, int out_size, void* d_ws, size_t ws_size,
                              hipStream_t stream) {
  const float* x    = (const float*)d_in[0];
  const float* kern = (const float*)d_in[1];
  const float* bias = (const float*)d_in[2];
  float* out = (float*)d_out;
  unsigned short* bt = (unsigned short*)d_ws;

  if (ws_size >= (size_t)WS_NEED) {
    prep_all<<<dim3(72 + 8192), dim3(256), 0, stream>>>(x, kern, bt);
    conv_main<true><<<dim3(4096), dim3(256), 0, stream>>>(x, bt, bias, out);
  } else {
    prep_all<<<dim3(72), dim3(256), 0, stream>>>(x, kern, bt);
    conv_main<false><<<dim3(4096), dim3(256), 0, stream>>>(x, bt, bias, out);
  }
}